// Round 14
// baseline (123.300 us; speedup 1.0000x reference)
//
#include <hip/hip_runtime.h>
#include <math.h>

namespace {
constexpr int kB = 4;
constexpr int kS = 4096;
constexpr int kH = 4096;
constexpr int kE = 16;
constexpr int kTokens = kB * kS;            // 16384
constexpr int kQ = 4;                       // H quarters
constexpr int kHQ = kH / kQ;                // 1024 floats per quarter
constexpr int kChunk = 256;                 // floats per j-iter (float4/lane)
constexpr int kNC = kHQ / kChunk;           // 4 chunks
constexpr int kWaves = 8;
constexpr int kThreads = 64 * kWaves;       // 512
constexpr int kT = 4;                       // tokens per wave (ALL 16 experts)
constexpr int kTokBlk = kT * kWaves;        // 32 tokens per block
constexpr int kGroups = kTokens / kTokBlk;  // 512 token groups
constexpr int kGridP = kGroups * kQ;        // 2048 partial blocks
constexpr int kThreadsF = 256;
constexpr int kGridF = kTokens / kThreadsF; // 64 finish blocks
}  // namespace

__device__ __forceinline__ void gload_lds16(const float* src_lane, float* lds_base) {
  // wave-uniform LDS base; HW adds lane*16. Linear dest + per-lane global src.
  __builtin_amdgcn_global_load_lds(
      (const __attribute__((address_space(1))) void*)src_lane,
      (__attribute__((address_space(3))) void*)lds_base, 16, 0, 0);
}

// Partial gate GEMM over one H-quarter. W-quarter (64 KiB) staged to LDS ONCE
// (single barrier — no per-chunk lockstep), then W reads ride the DS pipe
// instead of the saturated L1/TA vector-return port. x streams HBM->regs and
// is read exactly once chip-wide (each wave owns ALL 16 experts of its 4
// tokens). Zero runtime indexing of register arrays (rule #20).
__global__ __launch_bounds__(kThreads) void router_partial(
    const float* __restrict__ x, const float* __restrict__ W,
    float* __restrict__ partial) {   // [kQ][kTokens][kE]
  __shared__ float s_w[kE][kHQ];     // 64 KiB
  const int tid = threadIdx.x;
  const int wave = tid >> 6;
  const int lane = tid & 63;
  const int q = blockIdx.x >> 9;     // quarter 0..3 (512 blocks each)
  const int g = blockIdx.x & (kGroups - 1);
  const int tok0 = g * kTokBlk + wave * kT;

  // Stage: wave w covers W rows 2w, 2w+1 of this quarter (8 x 1KB gloads).
  {
    const int r0 = 2 * wave;
#pragma unroll
    for (int r = 0; r < 2; ++r)
#pragma unroll
      for (int c = 0; c < kNC; ++c)
        gload_lds16(W + (size_t)(r0 + r) * kH + q * kHQ + c * kChunk + lane * 4,
                    &s_w[r0 + r][c * kChunk]);
  }

  float acc[kT][kE];
#pragma unroll
  for (int t = 0; t < kT; ++t)
#pragma unroll
    for (int e = 0; e < kE; ++e) acc[t][e] = 0.f;

  const float* xb = x + (size_t)tok0 * kH + q * kHQ + lane * 4;

  __syncthreads();   // single barrier: staging vmcnt-drained, s_w resident

  auto load_x = [&](int j, float4 (&xv)[kT]) {
    const size_t off = (size_t)j * kChunk;
#pragma unroll
    for (int t = 0; t < kT; ++t)
      xv[t] = *reinterpret_cast<const float4*>(xb + (size_t)t * kH + off);
  };
  auto step = [&](int j, const float4 (&cur)[kT], float4 (&nxt)[kT], bool pf) {
    if (pf) load_x(j + 1, nxt);      // x(j+1) in flight through compute(j)
#pragma unroll
    for (int p = 0; p < 4; ++p) {
      float4 wv[4];
#pragma unroll
      for (int e = 0; e < 4; ++e)
        wv[e] = *reinterpret_cast<const float4*>(
            &s_w[p * 4 + e][j * kChunk + lane * 4]);
#pragma unroll
      for (int e = 0; e < 4; ++e) {
        const int ei = p * 4 + e;
#pragma unroll
        for (int t = 0; t < kT; ++t) {
          acc[t][ei] = fmaf(cur[t].x, wv[e].x, acc[t][ei]);
          acc[t][ei] = fmaf(cur[t].y, wv[e].y, acc[t][ei]);
          acc[t][ei] = fmaf(cur[t].z, wv[e].z, acc[t][ei]);
          acc[t][ei] = fmaf(cur[t].w, wv[e].w, acc[t][ei]);
        }
      }
    }
  };

  float4 xvA[kT], xvB[kT];
  load_x(0, xvA);
  step(0, xvA, xvB, true);
  step(1, xvB, xvA, true);
  step(2, xvA, xvB, true);
  step(3, xvB, xvA, false);

  // Butterfly: every lane ends with the quarter-sums for its 4x16 tile.
#pragma unroll
  for (int off = 1; off < 64; off <<= 1) {
#pragma unroll
    for (int t = 0; t < kT; ++t)
#pragma unroll
      for (int e = 0; e < kE; ++e)
        acc[t][e] += __shfl_xor(acc[t][e], off, 64);
  }

  // Publish partial logits — STATIC acc indices only (rule #20).
#pragma unroll
  for (int t = 0; t < kT; ++t) {
    if (lane == t) {
      float* dst = partial + ((size_t)q * kTokens + tok0 + t) * kE;
#pragma unroll
      for (int e = 0; e < kE; e += 4) {
        float4 v = make_float4(acc[t][e], acc[t][e + 1],
                               acc[t][e + 2], acc[t][e + 3]);
        *reinterpret_cast<float4*>(dst + e) = v;
      }
    }
  }
}

// Combine quarters, softmax, top-2, outputs, per-block aux partials.
__global__ __launch_bounds__(kThreadsF) void router_finish(
    const float* __restrict__ partial, float* __restrict__ out_probs,
    float* __restrict__ out_idx, float* __restrict__ gpart) {
  __shared__ float s_cnt[kE];
  __shared__ float s_psum[kE];
  const int tid = threadIdx.x;
  const int lane = tid & 63;
  const int tok = blockIdx.x * kThreadsF + tid;

  if (tid < kE) { s_cnt[tid] = 0.f; s_psum[tid] = 0.f; }
  __syncthreads();

  float l[kE];
#pragma unroll
  for (int e = 0; e < kE; ++e) l[e] = 0.f;
#pragma unroll
  for (int q = 0; q < kQ; ++q) {
    const float* src = partial + ((size_t)q * kTokens + tok) * kE;
#pragma unroll
    for (int e = 0; e < kE; e += 4) {
      const float4 v = *reinterpret_cast<const float4*>(src + e);
      l[e] += v.x; l[e + 1] += v.y; l[e + 2] += v.z; l[e + 3] += v.w;
    }
  }

  float m = l[0];
#pragma unroll
  for (int e = 1; e < kE; ++e) m = fmaxf(m, l[e]);
  float p[kE];
  float s = 0.f;
#pragma unroll
  for (int e = 0; e < kE; ++e) { p[e] = __expf(l[e] - m); s += p[e]; }
  const float inv = 1.f / s;
#pragma unroll
  for (int e = 0; e < kE; ++e) p[e] *= inv;

  // top-2 on probs (reference: top_k AFTER softmax; ties -> lowest index).
  // All p[] accesses at compile-time indices (no p[runtime] reads).
  int i1 = 0;
  float v1 = p[0];
#pragma unroll
  for (int e = 1; e < kE; ++e)
    if (p[e] > v1) { v1 = p[e]; i1 = e; }
  int i2 = -1;
  float v2 = -1.f;   // probs >= 0: first non-i1 max wins, lowest index on tie
#pragma unroll
  for (int e = 0; e < kE; ++e) {
    if (e == i1) continue;
    if (p[e] > v2) { v2 = p[e]; i2 = e; }
  }

  const float ns = 1.f / (v1 + v2);
  out_probs[tok * 2 + 0] = v1 * ns;
  out_probs[tok * 2 + 1] = v2 * ns;
  out_idx[tok * 2 + 0] = (float)i1;
  out_idx[tok * 2 + 1] = (float)i2;

  // psum: wave-butterfly then one atomic per wave per expert.
#pragma unroll
  for (int off = 1; off < 64; off <<= 1)
#pragma unroll
    for (int e = 0; e < kE; ++e) p[e] += __shfl_xor(p[e], off, 64);
  if (lane == 0)
#pragma unroll
    for (int e = 0; e < kE; ++e) atomicAdd(&s_psum[e], p[e]);
  atomicAdd(&s_cnt[i1], 1.f);
  atomicAdd(&s_cnt[i2], 1.f);

  __syncthreads();
  if (tid < 2 * kE)
    gpart[(size_t)blockIdx.x * 2 * kE + tid] =
        (tid < kE) ? s_cnt[tid] : s_psum[tid - kE];
}

// Reduce 64 block-partials; aux = E * sum_e (cnt_e/B) * (psum_e/(B*S)).
__global__ __launch_bounds__(1024) void aux_finish(
    const float* __restrict__ gpart, float* __restrict__ out_aux) {
  __shared__ float s_final[2 * kE];
  const int tid = threadIdx.x;
  const int c = tid >> 5;       // 0..31: partial column
  const int k = tid & 31;       // row pair index
  float s = gpart[(size_t)k * 32 + c] + gpart[(size_t)(k + 32) * 32 + c];
#pragma unroll
  for (int off = 1; off < 32; off <<= 1) s += __shfl_xor(s, off, 64);
  if (k == 0) s_final[c] = s;
  __syncthreads();
  if (tid == 0) {
    double acc = 0.0;
    for (int e = 0; e < kE; ++e)
      acc += (double)s_final[e] * (double)s_final[kE + e];
    out_aux[0] = (float)(acc * (double)kE / ((double)kB * (double)kB * (double)kS));
  }
}

extern "C" void kernel_launch(void* const* d_in, const int* in_sizes, int n_in,
                              void* d_out, int out_size, void* d_ws, size_t ws_size,
                              hipStream_t stream) {
  const float* x = (const float*)d_in[0];   // [B,S,H] f32
  const float* W = (const float*)d_in[1];   // [E,H]   f32
  float* out = (float*)d_out;               // [32768 probs][32768 idx][1 aux]
  float* partial = (float*)d_ws;            // [kQ][kTokens][kE] = 4 MiB
  float* gpart = partial + (size_t)kQ * kTokens * kE;  // [kGridF][32]

  router_partial<<<kGridP, kThreads, 0, stream>>>(x, W, partial);
  router_finish<<<kGridF, kThreadsF, 0, stream>>>(
      partial, out, out + 2 * kTokens, gpart);
  aux_finish<<<1, 1024, 0, stream>>>(gpart, out + 4 * kTokens);
}

// Round 15
// 118.759 us; speedup vs baseline: 1.0382x; 1.0382x over previous
//
#include <hip/hip_runtime.h>
#include <math.h>

namespace {
constexpr int kB = 4;
constexpr int kS = 4096;
constexpr int kH = 4096;
constexpr int kE = 16;
constexpr int kTokens = kB * kS;            // 16384
constexpr int kT = 8;                       // tokens per wave tile (W reuse x2)
constexpr int kEW = 8;                      // experts per wave tile (e-split 2)
constexpr int kThreads = 256;               // 4 waves: 2 token-groups x 2 e-halves
constexpr int kTokBlk = 16;                 // tokens per block
constexpr int kGrid = kTokens / kTokBlk;    // 1024 -> 4 blocks/CU, all resident
constexpr int kChunk = 256;                 // floats of H per j-iter (float4/lane)
constexpr int kNC = kH / kChunk;            // 16
}  // namespace

// R12's proven discipline (pure streaming, no LDS/barriers/waitcnt in the main
// loop, compiler-scheduled, ZERO runtime indexing of register arrays) with
// kT=8: each wave-tile's 8 W rows are amortized over 8 tokens instead of 4,
// halving W vector-port traffic (1 GB -> 512 MB chip-wide). Live registers:
// acc 64 + xv 32 + wv 16 + addr ~= 122; waves_per_eu(4,4) pins the 128-VGPR
// budget so the allocator neither spills (R6) nor starves ILP at 76 (R11).
__global__ __attribute__((amdgpu_waves_per_eu(4, 4)))
__launch_bounds__(kThreads) void router_main(
    const float* __restrict__ x, const float* __restrict__ W,
    float* __restrict__ out_probs,   // [kTokens][2]
    float* __restrict__ out_idx,     // [kTokens][2] (indices as float)
    float* __restrict__ gpart) {     // [kGrid][32]: cnt[16], psum[16] per block
  __shared__ float s_logit[kTokBlk][kE];
  __shared__ float s_cnt[kE];
  __shared__ float s_psum[kE];

  const int tid = threadIdx.x;
  const int wave = tid >> 6;
  const int lane = tid & 63;
  const int tg = wave >> 1;                 // token group: 0 or 1 (8 tokens each)
  const int eo = (wave & 1) * kEW;          // expert offset: 0 or 8
  const int tokBase = blockIdx.x * kTokBlk;
  const int tok0 = tokBase + tg * kT;

  if (tid < kE) { s_cnt[tid] = 0.f; s_psum[tid] = 0.f; }

  const float* xb = x + (size_t)tok0 * kH + lane * 4;
  const float* wb = W + (size_t)eo * kH + lane * 4;

  float acc[kT][kEW];
#pragma unroll
  for (int t = 0; t < kT; ++t)
#pragma unroll
    for (int e = 0; e < kEW; ++e) acc[t][e] = 0.f;

#pragma unroll 1
  for (int j = 0; j < kNC; ++j) {
    const size_t off = (size_t)j * kChunk;
    // x: 8 coalesced float4 (HBM stream) issued first -> 12 loads in flight
    // before the first consumer.
    float4 xv[kT];
#pragma unroll
    for (int t = 0; t < kT; ++t)
      xv[t] = *reinterpret_cast<const float4*>(xb + (size_t)t * kH + off);
    // W: 2 sub-phases x 4 rows (wv reused -> only 16 live regs for W).
#pragma unroll
    for (int p = 0; p < 2; ++p) {
      float4 wv[4];
#pragma unroll
      for (int e = 0; e < 4; ++e)
        wv[e] = *reinterpret_cast<const float4*>(
            wb + (size_t)(p * 4 + e) * kH + off);
#pragma unroll
      for (int e = 0; e < 4; ++e) {
        const int ei = p * 4 + e;
#pragma unroll
        for (int t = 0; t < kT; ++t) {
          acc[t][ei] = fmaf(xv[t].x, wv[e].x, acc[t][ei]);
          acc[t][ei] = fmaf(xv[t].y, wv[e].y, acc[t][ei]);
          acc[t][ei] = fmaf(xv[t].z, wv[e].z, acc[t][ei]);
          acc[t][ei] = fmaf(xv[t].w, wv[e].w, acc[t][ei]);
        }
      }
    }
  }

  // Butterfly: every lane ends with full-H sums for its 8x8 tile.
#pragma unroll
  for (int off = 1; off < 64; off <<= 1) {
#pragma unroll
    for (int t = 0; t < kT; ++t)
#pragma unroll
      for (int e = 0; e < kEW; ++e)
        acc[t][e] += __shfl_xor(acc[t][e], off, 64);
  }

  // Publish each token's 8-expert slice — STATIC acc indices only (rule #20).
#pragma unroll
  for (int t = 0; t < kT; ++t) {
    if (lane == t) {
      const int r = tg * kT + t;
#pragma unroll
      for (int e = 0; e < kEW; ++e) s_logit[r][eo + e] = acc[t][e];
    }
  }
  __syncthreads();

  // Wave 0, lanes 0..15: one token each — softmax, top-2, outputs, partials.
  if (wave == 0 && lane < kTokBlk) {
    const int tok = tokBase + lane;
    float l[kE];
#pragma unroll
    for (int e = 0; e < kE; ++e) l[e] = s_logit[lane][e];   // LDS: runtime ok

    float m = l[0];
#pragma unroll
    for (int e = 1; e < kE; ++e) m = fmaxf(m, l[e]);
    float p[kE];
    float s = 0.f;
#pragma unroll
    for (int e = 0; e < kE; ++e) { p[e] = __expf(l[e] - m); s += p[e]; }
    const float inv = 1.f / s;
#pragma unroll
    for (int e = 0; e < kE; ++e) p[e] *= inv;

    // top-2 on probs (reference: top_k AFTER softmax; ties -> lowest index).
    // All p[] accesses at compile-time indices (no p[runtime] reads).
    int i1 = 0;
    float v1 = p[0];
#pragma unroll
    for (int e = 1; e < kE; ++e)
      if (p[e] > v1) { v1 = p[e]; i1 = e; }
    int i2 = -1;
    float v2 = -1.f;   // probs >= 0: first non-i1 max wins, lowest index on tie
#pragma unroll
    for (int e = 0; e < kE; ++e) {
      if (e == i1) continue;
      if (p[e] > v2) { v2 = p[e]; i2 = e; }
    }

    const float ns = 1.f / (v1 + v2);
    out_probs[tok * 2 + 0] = v1 * ns;
    out_probs[tok * 2 + 1] = v2 * ns;
    out_idx[tok * 2 + 0] = (float)i1;
    out_idx[tok * 2 + 1] = (float)i2;

#pragma unroll
    for (int e = 0; e < kE; ++e) atomicAdd(&s_psum[e], p[e]);
    atomicAdd(&s_cnt[i1], 1.f);
    atomicAdd(&s_cnt[i2], 1.f);
  }
  __syncthreads();
  // Per-block partials (coalesced store); reduced by aux_finish.
  if (tid < 2 * kE)
    gpart[(size_t)blockIdx.x * 2 * kE + tid] =
        (tid < kE) ? s_cnt[tid] : s_psum[tid - kE];
}

// Reduce per-block partials; aux = E * sum_e (cnt_e/B) * (psum_e/(B*S)).
__global__ __launch_bounds__(1024) void aux_finish(
    const float* __restrict__ gpart, float* __restrict__ out_aux) {
  __shared__ float s_red[32][32];
  __shared__ float s_final[32];
  const int tid = threadIdx.x;
  const int c = tid & 31;       // column: 0-15 cnt, 16-31 psum
  const int r0 = tid >> 5;      // row-slice 0..31
  float s = 0.f;
  for (int k = 0; k < kGrid / 32; ++k)
    s += gpart[(size_t)(r0 * (kGrid / 32) + k) * 32 + c];
  s_red[r0][c] = s;
  __syncthreads();
  if (tid < 32) {
    float t = 0.f;
    for (int r = 0; r < 32; ++r) t += s_red[r][tid];
    s_final[tid] = t;
  }
  __syncthreads();
  if (tid == 0) {
    double acc = 0.0;
    for (int e = 0; e < kE; ++e)
      acc += (double)s_final[e] * (double)s_final[kE + e];
    out_aux[0] = (float)(acc * (double)kE / ((double)kB * (double)kB * (double)kS));
  }
}

extern "C" void kernel_launch(void* const* d_in, const int* in_sizes, int n_in,
                              void* d_out, int out_size, void* d_ws, size_t ws_size,
                              hipStream_t stream) {
  const float* x = (const float*)d_in[0];   // [B,S,H] f32
  const float* W = (const float*)d_in[1];   // [E,H]   f32
  float* out = (float*)d_out;               // [32768 probs][32768 idx][1 aux]
  float* gpart = (float*)d_ws;              // [kGrid][32], fully overwritten

  router_main<<<kGrid, kThreads, 0, stream>>>(
      x, W, out, out + 2 * kTokens, gpart);
  aux_finish<<<1, 1024, 0, stream>>>(gpart, out + 4 * kTokens);
}

// Round 16
// 89.036 us; speedup vs baseline: 1.3848x; 1.3338x over previous
//
#include <hip/hip_runtime.h>
#include <math.h>

namespace {
constexpr int kB = 4;
constexpr int kS = 4096;
constexpr int kH = 4096;
constexpr int kE = 16;
constexpr int kTokens = kB * kS;            // 16384
constexpr int kT = 2;                       // tokens per wave (ALL 16 experts)
constexpr int kWaves = 4;
constexpr int kThreads = 64 * kWaves;       // 256
constexpr int kTokBlk = kT * kWaves;        // 8 tokens per block
constexpr int kGrid = kTokens / kTokBlk;    // 2048
constexpr int kChunk = 256;                 // floats of H per panel (1 KB/row)
constexpr int kNP = kH / kChunk;            // 16 panels
}  // namespace

__device__ __forceinline__ void gload_lds16(const float* src_lane, float* lds_base) {
  // wave-uniform LDS base; HW adds lane*16. Linear dest + per-lane global src.
  __builtin_amdgcn_global_load_lds(
      (const __attribute__((address_space(1))) void*)src_lane,
      (__attribute__((address_space(3))) void*)lds_base, 16, 0, 0);
}

// W rides the DS pipe: per 256-float panel, the block stages W[16][256] (16KB)
// into a 2-slot LDS ring; each wave computes 2 tokens x ALL 16 experts
// (acc[2][16]=32 regs — the proven allocator sweet spot; x read ONCE
// chip-wide, no e-split dup). Pipeline: ONE raw s_barrier per panel, counted
// vmcnt(2), no drains ever:
//   A: vmcnt(2)  = own stage(p) landed (x(p), 2 newer ops, stays in flight)
//   B: s_barrier = all waves' stage(p) landed AND all done reading slot p-1
//      (each wave's compute(p-1) precedes its A(p), so B(p) orders it)
//   E: issue stage(p+1) [slot p-1's, safe by B] , fence, issue x(p+1)
//   C: compute panel p (ds_read W + x regs; compiler inserts lgkm/vm waits)
// Stage latency hides under C(p-1); x HBM latency spans a whole panel.
__global__ __launch_bounds__(kThreads) void router_main(
    const float* __restrict__ x, const float* __restrict__ W,
    float* __restrict__ out_probs,   // [kTokens][2]
    float* __restrict__ out_idx,     // [kTokens][2] (indices as float)
    float* __restrict__ gpart) {     // [kGrid][32]: cnt[16], psum[16] per block
  __shared__ float s_w[2][kE][kChunk];   // 32 KB ring
  __shared__ float s_logit[kTokBlk][kE];
  __shared__ float s_cnt[kE];
  __shared__ float s_psum[kE];

  const int tid = threadIdx.x;
  const int wave = tid >> 6;
  const int lane = tid & 63;
  const int tokBase = blockIdx.x * kTokBlk;
  const int tok0 = tokBase + kT * wave;     // this wave's 2 tokens

  if (tid < kE) { s_cnt[tid] = 0.f; s_psum[tid] = 0.f; }

  const float* xb = x + (size_t)tok0 * kH + lane * 4;
  const float* wb = W + (size_t)(4 * wave) * kH + lane * 4;  // stage rows 4w..4w+3

  float acc[kT][kE];
#pragma unroll
  for (int t = 0; t < kT; ++t)
#pragma unroll
    for (int e = 0; e < kE; ++e) acc[t][e] = 0.f;

  // Issue wave's share of panel p's W stage: 4 rows x 1 KB (4 gload_lds).
  auto stageW = [&](int p) {
    const int slot = p & 1;
    const size_t off = (size_t)p * kChunk;
#pragma unroll
    for (int i = 0; i < 4; ++i)
      gload_lds16(wb + (size_t)i * kH + off, &s_w[slot][4 * wave + i][0]);
  };
  auto loadx = [&](int p, float4 (&xv)[kT]) {
    const size_t off = (size_t)p * kChunk;
#pragma unroll
    for (int t = 0; t < kT; ++t)
      xv[t] = *reinterpret_cast<const float4*>(xb + (size_t)t * kH + off);
  };
  auto compute = [&](int slot, const float4 (&xv)[kT]) {
#pragma unroll
    for (int g = 0; g < 4; ++g) {
      float4 wv[4];
#pragma unroll
      for (int e = 0; e < 4; ++e)
        wv[e] = *reinterpret_cast<const float4*>(
            &s_w[slot][g * 4 + e][lane * 4]);
#pragma unroll
      for (int e = 0; e < 4; ++e) {
        const int ei = g * 4 + e;
#pragma unroll
        for (int t = 0; t < kT; ++t) {
          acc[t][ei] = fmaf(xv[t].x, wv[e].x, acc[t][ei]);
          acc[t][ei] = fmaf(xv[t].y, wv[e].y, acc[t][ei]);
          acc[t][ei] = fmaf(xv[t].z, wv[e].z, acc[t][ei]);
          acc[t][ei] = fmaf(xv[t].w, wv[e].w, acc[t][ei]);
        }
      }
    }
  };

  float4 xvA[kT], xvB[kT];

  // Prologue: stage(0) then x(0) (order pinned: vmcnt counts depend on it).
  stageW(0);
  asm volatile("" ::: "memory");
  loadx(0, xvA);
  asm volatile("" ::: "memory");

#pragma unroll 1
  for (int pp = 0; pp < kNP; pp += 2) {
    // ---- panel pp (even, slot 0, xvA) ----
    asm volatile("s_waitcnt vmcnt(2)" ::: "memory");   // stage(pp) done
    __builtin_amdgcn_s_barrier();
    asm volatile("" ::: "memory");
    stageW(pp + 1);
    asm volatile("" ::: "memory");
    loadx(pp + 1, xvB);
    asm volatile("" ::: "memory");
    compute(0, xvA);

    // ---- panel pp+1 (odd, slot 1, xvB) ----
    asm volatile("s_waitcnt vmcnt(2)" ::: "memory");   // stage(pp+1) done
    __builtin_amdgcn_s_barrier();
    asm volatile("" ::: "memory");
    if (pp + 2 < kNP) {
      stageW(pp + 2);
      asm volatile("" ::: "memory");
      loadx(pp + 2, xvA);
      asm volatile("" ::: "memory");
    }
    compute(1, xvB);
  }

  // Butterfly: every lane ends with full-H sums for its 2x16 tile.
#pragma unroll
  for (int off = 1; off < 64; off <<= 1) {
#pragma unroll
    for (int t = 0; t < kT; ++t)
#pragma unroll
      for (int e = 0; e < kE; ++e)
        acc[t][e] += __shfl_xor(acc[t][e], off, 64);
  }

  // Publish logits — STATIC acc indices only (rule #20).
#pragma unroll
  for (int t = 0; t < kT; ++t) {
    if (lane == t) {
      const int r = kT * wave + t;
#pragma unroll
      for (int e = 0; e < kE; ++e) s_logit[r][e] = acc[t][e];
    }
  }
  __syncthreads();

  // Wave 0, lanes 0..7: one token each — softmax, top-2, outputs, partials.
  if (wave == 0 && lane < kTokBlk) {
    const int tok = tokBase + lane;
    float l[kE];
#pragma unroll
    for (int e = 0; e < kE; ++e) l[e] = s_logit[lane][e];   // LDS: runtime ok

    float m = l[0];
#pragma unroll
    for (int e = 1; e < kE; ++e) m = fmaxf(m, l[e]);
    float p[kE];
    float s = 0.f;
#pragma unroll
    for (int e = 0; e < kE; ++e) { p[e] = __expf(l[e] - m); s += p[e]; }
    const float inv = 1.f / s;
#pragma unroll
    for (int e = 0; e < kE; ++e) p[e] *= inv;

    // top-2 on probs (reference: top_k AFTER softmax; ties -> lowest index).
    int i1 = 0;
    float v1 = p[0];
#pragma unroll
    for (int e = 1; e < kE; ++e)
      if (p[e] > v1) { v1 = p[e]; i1 = e; }
    int i2 = -1;
    float v2 = -1.f;   // probs >= 0: first non-i1 max wins, lowest index on tie
#pragma unroll
    for (int e = 0; e < kE; ++e) {
      if (e == i1) continue;
      if (p[e] > v2) { v2 = p[e]; i2 = e; }
    }

    const float ns = 1.f / (v1 + v2);
    out_probs[tok * 2 + 0] = v1 * ns;
    out_probs[tok * 2 + 1] = v2 * ns;
    out_idx[tok * 2 + 0] = (float)i1;
    out_idx[tok * 2 + 1] = (float)i2;

#pragma unroll
    for (int e = 0; e < kE; ++e) atomicAdd(&s_psum[e], p[e]);
    atomicAdd(&s_cnt[i1], 1.f);
    atomicAdd(&s_cnt[i2], 1.f);
  }
  __syncthreads();
  // Per-block partials (coalesced store); reduced by aux_finish.
  if (tid < 2 * kE)
    gpart[(size_t)blockIdx.x * 2 * kE + tid] =
        (tid < kE) ? s_cnt[tid] : s_psum[tid - kE];
}

// Reduce per-block partials; aux = E * sum_e (cnt_e/B) * (psum_e/(B*S)).
__global__ __launch_bounds__(1024) void aux_finish(
    const float* __restrict__ gpart, float* __restrict__ out_aux) {
  __shared__ float s_red[32][32];
  __shared__ float s_final[32];
  const int tid = threadIdx.x;
  const int c = tid & 31;       // column: 0-15 cnt, 16-31 psum
  const int r0 = tid >> 5;      // row-slice 0..31
  float s = 0.f;
  for (int k = 0; k < kGrid / 32; ++k)
    s += gpart[(size_t)(r0 * (kGrid / 32) + k) * 32 + c];
  s_red[r0][c] = s;
  __syncthreads();
  if (tid < 32) {
    float t = 0.f;
    for (int r = 0; r < 32; ++r) t += s_red[r][tid];
    s_final[tid] = t;
  }
  __syncthreads();
  if (tid == 0) {
    double acc = 0.0;
    for (int e = 0; e < kE; ++e)
      acc += (double)s_final[e] * (double)s_final[kE + e];
    out_aux[0] = (float)(acc * (double)kE / ((double)kB * (double)kB * (double)kS));
  }
}

extern "C" void kernel_launch(void* const* d_in, const int* in_sizes, int n_in,
                              void* d_out, int out_size, void* d_ws, size_t ws_size,
                              hipStream_t stream) {
  const float* x = (const float*)d_in[0];   // [B,S,H] f32
  const float* W = (const float*)d_in[1];   // [E,H]   f32
  float* out = (float*)d_out;               // [32768 probs][32768 idx][1 aux]
  float* gpart = (float*)d_ws;              // [kGrid][32], fully overwritten

  router_main<<<kGrid, kThreads, 0, stream>>>(
      x, W, out, out + 2 * kTokens, gpart);
  aux_finish<<<1, 1024, 0, stream>>>(gpart, out + 4 * kTokens);
}

// Round 17
// 81.118 us; speedup vs baseline: 1.5200x; 1.0976x over previous
//
#include <hip/hip_runtime.h>
#include <math.h>

namespace {
constexpr int kB = 4;
constexpr int kS = 4096;
constexpr int kH = 4096;
constexpr int kE = 16;
constexpr int kTokens = kB * kS;            // 16384
constexpr int kT = 4;                       // tokens per wave tile
constexpr int kEW = 8;                      // experts per wave tile (e-split 2)
constexpr int kThreads = 256;               // 4 waves: 2 token-groups x 2 e-halves
constexpr int kTokBlk = 8;                  // tokens per block
constexpr int kGrid = kTokens / kTokBlk;    // 2048
constexpr int kChunk = 256;                 // floats of H per j-iter (float4/lane)
constexpr int kNC = kH / kChunk;            // 16
}  // namespace

// Best measured configuration (R13: 83.6 us). Pure-streaming gate GEMM:
// no LDS / barriers / manual waitcnt in the main loop (compiler schedules —
// every manual-scheduling attempt regressed), 4 tok x 8 exp wave tile
// (acc[4][8]=32 regs, the allocator sweet spot; acc-64 tiles always demote
// to scratch on this toolchain), depth-1 x prefetch via named ping-pong
// arrays, ZERO runtime indexing of register arrays anywhere (rule #20 —
// a single acc[lane][e] read demotes the whole accumulator to scratch).
__global__ __launch_bounds__(kThreads) void router_main(
    const float* __restrict__ x, const float* __restrict__ W,
    float* __restrict__ out_probs,   // [kTokens][2]
    float* __restrict__ out_idx,     // [kTokens][2] (indices as float)
    float* __restrict__ gpart) {     // [kGrid][32]: cnt[16], psum[16] per block
  __shared__ float s_logit[kTokBlk][kE];
  __shared__ float s_cnt[kE];
  __shared__ float s_psum[kE];

  const int tid = threadIdx.x;
  const int wave = tid >> 6;
  const int lane = tid & 63;
  const int tg = wave >> 1;                 // token group: 0 or 1
  const int eo = (wave & 1) * kEW;          // expert offset: 0 or 8
  const int tokBase = blockIdx.x * kTokBlk;
  const int tok0 = tokBase + tg * kT;

  if (tid < kE) { s_cnt[tid] = 0.f; s_psum[tid] = 0.f; }

  const float* xb = x + (size_t)tok0 * kH + lane * 4;
  const float* wb = W + (size_t)eo * kH + lane * 4;

  float acc[kT][kEW];
#pragma unroll
  for (int t = 0; t < kT; ++t)
#pragma unroll
    for (int e = 0; e < kEW; ++e) acc[t][e] = 0.f;

  auto load_x = [&](int j, float4 (&xv)[kT]) {
    const size_t off = (size_t)j * kChunk;
#pragma unroll
    for (int t = 0; t < kT; ++t)
      xv[t] = *reinterpret_cast<const float4*>(xb + (size_t)t * kH + off);
  };

  // One j-step: prefetch x(j+1) into `nxt` FIRST, then W loads + FMAs on `cur`.
  auto step = [&](int j, const float4 (&cur)[kT], float4 (&nxt)[kT], bool pf) {
    if (pf) load_x(j + 1, nxt);
    const size_t off = (size_t)j * kChunk;
#pragma unroll
    for (int p = 0; p < 2; ++p) {
      float4 wv[4];
#pragma unroll
      for (int e = 0; e < 4; ++e)
        wv[e] = *reinterpret_cast<const float4*>(
            wb + (size_t)(p * 4 + e) * kH + off);
#pragma unroll
      for (int e = 0; e < 4; ++e) {
        const int ei = p * 4 + e;
#pragma unroll
        for (int t = 0; t < kT; ++t) {
          acc[t][ei] = fmaf(cur[t].x, wv[e].x, acc[t][ei]);
          acc[t][ei] = fmaf(cur[t].y, wv[e].y, acc[t][ei]);
          acc[t][ei] = fmaf(cur[t].z, wv[e].z, acc[t][ei]);
          acc[t][ei] = fmaf(cur[t].w, wv[e].w, acc[t][ei]);
        }
      }
    }
  };

  float4 xvA[kT], xvB[kT];
  load_x(0, xvA);

#pragma unroll 1
  for (int j = 0; j < kNC; j += 2) {
    step(j, xvA, xvB, true);                 // uses x(j),   prefetches x(j+1)
    step(j + 1, xvB, xvA, j + 2 < kNC);      // uses x(j+1), prefetches x(j+2)
  }

  // Butterfly: every lane ends with full-H sums for its 4x8 tile.
#pragma unroll
  for (int off = 1; off < 64; off <<= 1) {
#pragma unroll
    for (int t = 0; t < kT; ++t)
#pragma unroll
      for (int e = 0; e < kEW; ++e)
        acc[t][e] += __shfl_xor(acc[t][e], off, 64);
  }

  // Publish each token's 8-expert slice — STATIC acc indices only (rule #20).
#pragma unroll
  for (int t = 0; t < kT; ++t) {
    if (lane == t) {
      const int r = tg * kT + t;
#pragma unroll
      for (int e = 0; e < kEW; ++e) s_logit[r][eo + e] = acc[t][e];
    }
  }
  __syncthreads();

  // Wave 0, lanes 0..7: one token each — softmax, top-2, outputs, aux partials.
  if (wave == 0 && lane < kTokBlk) {
    const int tok = tokBase + lane;
    float l[kE];
#pragma unroll
    for (int e = 0; e < kE; ++e) l[e] = s_logit[lane][e];   // LDS: runtime ok

    float m = l[0];
#pragma unroll
    for (int e = 1; e < kE; ++e) m = fmaxf(m, l[e]);
    float p[kE];
    float s = 0.f;
#pragma unroll
    for (int e = 0; e < kE; ++e) { p[e] = __expf(l[e] - m); s += p[e]; }
    const float inv = 1.f / s;
#pragma unroll
    for (int e = 0; e < kE; ++e) p[e] *= inv;

    // top-2 on probs (reference: top_k AFTER softmax; ties -> lowest index).
    // All p[] accesses at compile-time indices (no p[i1]/p[i2] reads).
    int i1 = 0;
    float v1 = p[0];
#pragma unroll
    for (int e = 1; e < kE; ++e)
      if (p[e] > v1) { v1 = p[e]; i1 = e; }
    int i2 = -1;
    float v2 = -1.f;   // probs >= 0: first non-i1 max wins, lowest index on tie
#pragma unroll
    for (int e = 0; e < kE; ++e) {
      if (e == i1) continue;
      if (p[e] > v2) { v2 = p[e]; i2 = e; }
    }

    const float ns = 1.f / (v1 + v2);
    out_probs[tok * 2 + 0] = v1 * ns;
    out_probs[tok * 2 + 1] = v2 * ns;
    out_idx[tok * 2 + 0] = (float)i1;
    out_idx[tok * 2 + 1] = (float)i2;

#pragma unroll
    for (int e = 0; e < kE; ++e) atomicAdd(&s_psum[e], p[e]);
    atomicAdd(&s_cnt[i1], 1.f);
    atomicAdd(&s_cnt[i2], 1.f);
  }
  __syncthreads();
  // Per-block partials (coalesced store); reduced by aux_finish.
  if (tid < 2 * kE)
    gpart[(size_t)blockIdx.x * 2 * kE + tid] =
        (tid < kE) ? s_cnt[tid] : s_psum[tid - kE];
}

// Reduce per-block partials; aux = E * sum_e (cnt_e/B) * (psum_e/(B*S)).
__global__ __launch_bounds__(1024) void aux_finish(
    const float* __restrict__ gpart, float* __restrict__ out_aux) {
  __shared__ float s_red[32][32];
  __shared__ float s_final[32];
  const int tid = threadIdx.x;
  const int c = tid & 31;       // column: 0-15 cnt, 16-31 psum
  const int r0 = tid >> 5;      // row-slice 0..31
  float s = 0.f;
  for (int k = 0; k < kGrid / 32; ++k)
    s += gpart[(size_t)(r0 * (kGrid / 32) + k) * 32 + c];
  s_red[r0][c] = s;
  __syncthreads();
  if (tid < 32) {
    float t = 0.f;
    for (int r = 0; r < 32; ++r) t += s_red[r][tid];
    s_final[tid] = t;
  }
  __syncthreads();
  if (tid == 0) {
    double acc = 0.0;
    for (int e = 0; e < kE; ++e)
      acc += (double)s_final[e] * (double)s_final[kE + e];
    out_aux[0] = (float)(acc * (double)kE / ((double)kB * (double)kB * (double)kS));
  }
}

extern "C" void kernel_launch(void* const* d_in, const int* in_sizes, int n_in,
                              void* d_out, int out_size, void* d_ws, size_t ws_size,
                              hipStream_t stream) {
  const float* x = (const float*)d_in[0];   // [B,S,H] f32
  const float* W = (const float*)d_in[1];   // [E,H]   f32
  float* out = (float*)d_out;               // [32768 probs][32768 idx][1 aux]
  float* gpart = (float*)d_ws;              // [kGrid][32], fully overwritten

  router_main<<<kGrid, kThreads, 0, stream>>>(
      x, W, out, out + 2 * kTokens, gpart);
  aux_finish<<<1, 1024, 0, stream>>>(gpart, out + 4 * kTokens);
}